// Round 18
// baseline (179.170 us; speedup 1.0000x reference)
//
#include <hip/hip_runtime.h>
#include <hip/hip_fp16.h>

#ifndef __has_builtin
#define __has_builtin(x) 0
#endif

#define N_NODES 50000
#define N_EDGES 800000
#define DIM 64
#define NH 4
#define LN_EPS 1e-5f
#define SLOPE 0.2f
#define LOG2E 1.44269504f
#define PBLOCKS 782      // proj: 782 blocks x 64 nodes >= 50000
#define BCAP 64          // bucket capacity; P(Poisson(16) > 64) ~ 1e-18 per node

typedef _Float16 half4v __attribute__((ext_vector_type(4)));
typedef float floatx4 __attribute__((ext_vector_type(4)));

__device__ __forceinline__ float lrelu(float v){ return v > 0.f ? v : SLOPE * v; }

__device__ __forceinline__ float waveSum64(float v){
  v += __shfl_xor(v, 1);  v += __shfl_xor(v, 2);  v += __shfl_xor(v, 4);
  v += __shfl_xor(v, 8);  v += __shfl_xor(v, 16); v += __shfl_xor(v, 32);
  return v;
}

__device__ __forceinline__ __half2 u2h2(unsigned u){ union{unsigned u; __half2 h;} c; c.u = u; return c.h; }
__device__ __forceinline__ unsigned h22u(__half2 h){ union{unsigned u; __half2 h;} c; c.h = h; return c.u; }

// packed f16 max (no __hmax2 in ROCm headers) -> v_pk_max_f16
__device__ __forceinline__ __half2 hmax2(__half2 a, __half2 b){
  unsigned ua = h22u(a), ub = h22u(b), r;
  asm("v_pk_max_f16 %0, %1, %2" : "=v"(r) : "v"(ua), "v"(ub));
  return u2h2(r);
}

// f32 += dot(h2, h2) : v_dot2_f32_f16
__device__ __forceinline__ float fdot2f(unsigned a, unsigned b, float c){
#if __has_builtin(__builtin_amdgcn_fdot2)
  typedef _Float16 h2v __attribute__((ext_vector_type(2)));
  union U{unsigned u; h2v h;};
  U ua, ub; ua.u = a; ub.u = b;
  return __builtin_amdgcn_fdot2(ua.h, ub.h, c, false);
#else
  float r;
  asm("v_dot2_f32_f16 %0, %1, %2, %3" : "=v"(r) : "v"(a), "v"(b), "v"(c));
  return r;
#endif
}

__device__ __forceinline__ float exp2fast(float x){
#if __has_builtin(__builtin_amdgcn_exp2f)
  return __builtin_amdgcn_exp2f(x);
#else
  float r; asm("v_exp_f32 %0, %1" : "=v"(r) : "v"(x)); return r;
#endif
}

// single 16-lane row reduce (tail / epilogue use)
__device__ __forceinline__ float sum16fast(float v){
  asm("s_nop 1\n\t"
      "v_add_f32_dpp %0, %0, %0 quad_perm:[1,0,3,2] row_mask:0xf bank_mask:0xf\n\t"
      "s_nop 1\n\t"
      "v_add_f32_dpp %0, %0, %0 quad_perm:[2,3,0,1] row_mask:0xf bank_mask:0xf\n\t"
      "s_nop 1\n\t"
      "v_add_f32_dpp %0, %0, %0 row_ror:4 row_mask:0xf bank_mask:0xf\n\t"
      "s_nop 1\n\t"
      "v_add_f32_dpp %0, %0, %0 row_ror:8 row_mask:0xf bank_mask:0xf"
      : "+v"(v));
  return v;
}

// quad 16-lane reduce: 4 independent chains interleaved -> zero hazard nops
__device__ __forceinline__ void sum16quad(float& a, float& b, float& c, float& d){
  asm("v_add_f32_dpp %0, %0, %0 quad_perm:[1,0,3,2] row_mask:0xf bank_mask:0xf\n\t"
      "v_add_f32_dpp %1, %1, %1 quad_perm:[1,0,3,2] row_mask:0xf bank_mask:0xf\n\t"
      "v_add_f32_dpp %2, %2, %2 quad_perm:[1,0,3,2] row_mask:0xf bank_mask:0xf\n\t"
      "v_add_f32_dpp %3, %3, %3 quad_perm:[1,0,3,2] row_mask:0xf bank_mask:0xf\n\t"
      "v_add_f32_dpp %0, %0, %0 quad_perm:[2,3,0,1] row_mask:0xf bank_mask:0xf\n\t"
      "v_add_f32_dpp %1, %1, %1 quad_perm:[2,3,0,1] row_mask:0xf bank_mask:0xf\n\t"
      "v_add_f32_dpp %2, %2, %2 quad_perm:[2,3,0,1] row_mask:0xf bank_mask:0xf\n\t"
      "v_add_f32_dpp %3, %3, %3 quad_perm:[2,3,0,1] row_mask:0xf bank_mask:0xf\n\t"
      "v_add_f32_dpp %0, %0, %0 row_ror:4 row_mask:0xf bank_mask:0xf\n\t"
      "v_add_f32_dpp %1, %1, %1 row_ror:4 row_mask:0xf bank_mask:0xf\n\t"
      "v_add_f32_dpp %2, %2, %2 row_ror:4 row_mask:0xf bank_mask:0xf\n\t"
      "v_add_f32_dpp %3, %3, %3 row_ror:4 row_mask:0xf bank_mask:0xf\n\t"
      "v_add_f32_dpp %0, %0, %0 row_ror:8 row_mask:0xf bank_mask:0xf\n\t"
      "v_add_f32_dpp %1, %1, %1 row_ror:8 row_mask:0xf bank_mask:0xf\n\t"
      "v_add_f32_dpp %2, %2, %2 row_ror:8 row_mask:0xf bank_mask:0xf\n\t"
      "v_add_f32_dpp %3, %3, %3 row_ror:8 row_mask:0xf bank_mask:0xf"
      : "+v"(a), "+v"(b), "+v"(c), "+v"(d));
}

// ---------------------------------------------------------------------------
// 1) fill: standalone edge bucketing, 1 edge/thread, max occupancy -> 800K
// independent atomic/scatter chains in flight. Fused: FFN weight packing.
// ---------------------------------------------------------------------------
__global__ void fill_kernel(const int* __restrict__ ei, const float* __restrict__ ea,
                            int* __restrict__ cursor, uint2* __restrict__ buckets,
                            const float* __restrict__ W1, const float* __restrict__ W2,
                            unsigned* __restrict__ W1p, unsigned* __restrict__ W2p){
  const int gid = blockIdx.x * blockDim.x + threadIdx.x;
  if (gid < 4096){
    int kk = gid >> 7, cc = gid & 127;
    W1p[gid] = h22u(__floats2half2_rn(W1[(2 * kk) * 128 + cc], W1[(2 * kk + 1) * 128 + cc]));
  } else if (gid < 8192){
    int j = gid - 4096;
    int kk = j >> 6, cc = j & 63;
    W2p[j] = h22u(__floats2half2_rn(W2[(2 * kk) * 64 + cc], W2[(2 * kk + 1) * 64 + cc]));
  }
  if (gid >= N_EDGES) return;
  const int dst = ei[N_EDGES + gid];
  const int src = ei[gid];
  const float e0 = ea[gid * 3 + 0], e1 = ea[gid * 3 + 1], e2 = ea[gid * 3 + 2];
  int pos = atomicAdd(&cursor[dst], 1);
  pos = min(pos, BCAP - 1);   // unreachable in practice
  uint2 v;
  v.x = h22u(__floats2half2_rn(e0, e1));
  v.y = (h22u(__floats2half2_rn(e2, 0.f)) & 0xffffu) | ((unsigned)src << 16);
  buckets[(size_t)dst * BCAP + pos] = v;
}

// ---------------------------------------------------------------------------
// 2) proj: PURE MFMA GEMM (v_mfma_f32_16x16x16f16). Block = 4 waves x 64
// nodes; wave w owns cols [128w,128w+128), B-frags in regs (loaded once).
// ot padded to [16][520]: rows 16B-aligned (uint4 reads) and 4-row bank
// offset 16 -> at most 2-way LDS aliasing (r17 had 800K conflicts at 512).
// ---------------------------------------------------------------------------
__global__ __launch_bounds__(256)
void proj_kernel(const float* __restrict__ x,
                 const float* __restrict__ Wl, const float* __restrict__ bl,
                 const float* __restrict__ Wr, const float* __restrict__ br,
                 __half* __restrict__ xlh, __half* __restrict__ xrh){
  __shared__ __half ot[16][520];     // 16.25 KB output staging (padded)
  const int tid = threadIdx.x;
  const int lane = tid & 63, w = tid >> 6;
  const int row = lane & 15, kg = lane >> 4;

  // ---- B fragments (once per wave; reused over 4 M-tiles) ----
  const int colb = w * 128;
  const bool isL = colb < 256;
  const float* Wb = isL ? Wl : Wr;
  const float* bb = isL ? bl : br;
  const int cl = colb & 255;
  half4v bf[8][4];
  float bias[8];
#pragma unroll
  for (int nt = 0; nt < 8; ++nt){
    const int c = cl + nt * 16 + row;
    bias[nt] = bb[c];
#pragma unroll
    for (int kc = 0; kc < 4; ++kc){
      half4v b;
#pragma unroll
      for (int e = 0; e < 4; ++e)
        b[e] = (_Float16)Wb[(kc * 16 + kg * 4 + e) * 256 + c];
      bf[nt][kc] = b;
    }
  }

  // ---- M loop: 4 tiles of 16 nodes ----
  const int nbase = blockIdx.x * 64;
  for (int m = 0; m < 4; ++m){
    const int nb = nbase + m * 16;
    if (nb >= N_NODES) break;
    const int nld = min(nb + row, N_NODES - 1);
    half4v af[4];
#pragma unroll
    for (int kc = 0; kc < 4; ++kc){
      const float4 xv = *(const float4*)&x[(size_t)nld * 64 + kc * 16 + kg * 4];
      half4v a;
      a[0] = (_Float16)xv.x; a[1] = (_Float16)xv.y;
      a[2] = (_Float16)xv.z; a[3] = (_Float16)xv.w;
      af[kc] = a;
    }
    __syncthreads();   // ot free from previous tile's stores
#pragma unroll
    for (int nt = 0; nt < 8; ++nt){
      floatx4 acc = {0.f, 0.f, 0.f, 0.f};
      acc = __builtin_amdgcn_mfma_f32_16x16x16f16(af[0], bf[nt][0], acc, 0, 0, 0);
      acc = __builtin_amdgcn_mfma_f32_16x16x16f16(af[1], bf[nt][1], acc, 0, 0, 0);
      acc = __builtin_amdgcn_mfma_f32_16x16x16f16(af[2], bf[nt][2], acc, 0, 0, 0);
      acc = __builtin_amdgcn_mfma_f32_16x16x16f16(af[3], bf[nt][3], acc, 0, 0, 0);
      const int c = w * 128 + nt * 16 + row;
#pragma unroll
      for (int r = 0; r < 4; ++r)
        ot[kg * 4 + r][c] = __float2half(acc[r] + bias[nt]);
    }
    __syncthreads();
    // coalesced store: 1024 uint4 per tile, 4 per thread
#pragma unroll
    for (int s = 0; s < 4; ++s){
      const int idx = s * 256 + tid;
      const int r = idx >> 6, q = idx & 63;
      const int n = nb + r;
      if (n < N_NODES){
        const uint4 v = *(const uint4*)&ot[r][q * 8];
        if (q < 32) *(uint4*)(xlh + (size_t)n * 256 + q * 8) = v;
        else        *(uint4*)(xrh + (size_t)n * 256 + (q - 32) * 8) = v;
      }
    }
  }
}

// ---------------------------------------------------------------------------
// 3) FUSED GATv2: logits + segment softmax + aggregation + self-loop
//    + head mean + gat_b + residual + LN1.  ONE WAVE = ONE BLOCK = ONE NODE
// ---------------------------------------------------------------------------
#define EDGE_MATH(he0, he1, he2, a01, a23, p)                                        \
  {                                                                                  \
    __half2 z01 = __hadd2(a01, xr01);                                                \
    z01 = __hfma2(u2h2(he0), w0a, z01);                                              \
    z01 = __hfma2(u2h2(he1), w1a, z01);                                              \
    z01 = __hfma2(u2h2(he2), w2a, z01);                                              \
    __half2 z23 = __hadd2(a23, xr23);                                                \
    z23 = __hfma2(u2h2(he0), w0b, z23);                                              \
    z23 = __hfma2(u2h2(he1), w1b, z23);                                              \
    z23 = __hfma2(u2h2(he2), w2b, z23);                                              \
    z01 = hmax2(z01, __hmul2(z01, slp));                                             \
    z23 = hmax2(z23, __hmul2(z23, slp));                                             \
    p = fdot2f(h22u(z01), awa, fdot2f(h22u(z23), awb, 0.f));                         \
  }

__global__ __launch_bounds__(64)
void aggregate_kernel(const int* __restrict__ cursor, const uint2* __restrict__ buckets,
                      const __half* __restrict__ xlh, const __half* __restrict__ xrh,
                      const float* __restrict__ We, const float* __restrict__ att,
                      const float* __restrict__ x, const float* __restrict__ gat_b,
                      const float* __restrict__ ln1g, const float* __restrict__ ln1b,
                      __half* __restrict__ h1h){
  const int n = blockIdx.x;
  const int lane = threadIdx.x;
  const int j0 = lane * 4;
  const unsigned awa = h22u(__floats2half2_rn(att[j0] * LOG2E, att[j0 + 1] * LOG2E));
  const unsigned awb = h22u(__floats2half2_rn(att[j0 + 2] * LOG2E, att[j0 + 3] * LOG2E));
  const __half2 w0a = __floats2half2_rn(We[j0], We[j0 + 1]);
  const __half2 w0b = __floats2half2_rn(We[j0 + 2], We[j0 + 3]);
  const __half2 w1a = __floats2half2_rn(We[256 + j0], We[256 + j0 + 1]);
  const __half2 w1b = __floats2half2_rn(We[256 + j0 + 2], We[256 + j0 + 3]);
  const __half2 w2a = __floats2half2_rn(We[512 + j0], We[512 + j0 + 1]);
  const __half2 w2b = __floats2half2_rn(We[512 + j0 + 2], We[512 + j0 + 3]);
  const __half2 slp = __float2half2_rn(SLOPE);
  uint2 uxr = *(const uint2*)(xrh + (size_t)n * 256 + j0);
  const __half2 xr01 = u2h2(uxr.x), xr23 = u2h2(uxr.y);

  __half2 acc01 = __float2half2_rn(0.f), acc23 = __float2half2_rn(0.f);
  float den = 0.f;
  const int deg = min(cursor[n], BCAP);
  uint2 m2; m2.x = 0; m2.y = 0;
  if (lane < deg) m2 = buckets[(size_t)n * BCAP + lane];
  float s0 = __low2float(u2h2(m2.x));
  float s1 = __high2float(u2h2(m2.x));
  float s2 = __low2float(u2h2(m2.y & 0xffffu));
  int j = 0;
  for (; j + 4 <= deg; j += 4){
    const unsigned sxA = (unsigned)__builtin_amdgcn_readlane((int)m2.x, j);
    const unsigned syA = (unsigned)__builtin_amdgcn_readlane((int)m2.y, j);
    const unsigned sxB = (unsigned)__builtin_amdgcn_readlane((int)m2.x, j + 1);
    const unsigned syB = (unsigned)__builtin_amdgcn_readlane((int)m2.y, j + 1);
    const unsigned sxC = (unsigned)__builtin_amdgcn_readlane((int)m2.x, j + 2);
    const unsigned syC = (unsigned)__builtin_amdgcn_readlane((int)m2.y, j + 2);
    const unsigned sxD = (unsigned)__builtin_amdgcn_readlane((int)m2.x, j + 3);
    const unsigned syD = (unsigned)__builtin_amdgcn_readlane((int)m2.y, j + 3);
    uint2 uA = *(const uint2*)(xlh + (size_t)(syA >> 16) * 256 + j0);
    uint2 uB = *(const uint2*)(xlh + (size_t)(syB >> 16) * 256 + j0);
    uint2 uC = *(const uint2*)(xlh + (size_t)(syC >> 16) * 256 + j0);
    uint2 uD = *(const uint2*)(xlh + (size_t)(syD >> 16) * 256 + j0);
    const unsigned heA0 = (sxA & 0xffffu) | (sxA << 16), heA1 = (sxA >> 16) | (sxA & 0xffff0000u), heA2 = (syA & 0xffffu) | (syA << 16);
    const unsigned heB0 = (sxB & 0xffffu) | (sxB << 16), heB1 = (sxB >> 16) | (sxB & 0xffff0000u), heB2 = (syB & 0xffffu) | (syB << 16);
    const unsigned heC0 = (sxC & 0xffffu) | (sxC << 16), heC1 = (sxC >> 16) | (sxC & 0xffff0000u), heC2 = (syC & 0xffffu) | (syC << 16);
    const unsigned heD0 = (sxD & 0xffffu) | (sxD << 16), heD1 = (sxD >> 16) | (sxD & 0xffff0000u), heD2 = (syD & 0xffffu) | (syD << 16);
    const __half2 aA01 = u2h2(uA.x), aA23 = u2h2(uA.y);
    const __half2 aB01 = u2h2(uB.x), aB23 = u2h2(uB.y);
    const __half2 aC01 = u2h2(uC.x), aC23 = u2h2(uC.y);
    const __half2 aD01 = u2h2(uD.x), aD23 = u2h2(uD.y);
    float pA, pB, pC, pD;
    EDGE_MATH(heA0, heA1, heA2, aA01, aA23, pA)
    EDGE_MATH(heB0, heB1, heB2, aB01, aB23, pB)
    EDGE_MATH(heC0, heC1, heC2, aC01, aC23, pC)
    EDGE_MATH(heD0, heD1, heD2, aD01, aD23, pD)
    sum16quad(pA, pB, pC, pD);
    float wA = exp2fast(pA), wB = exp2fast(pB);
    float wC = exp2fast(pC), wD = exp2fast(pD);
    __half2 whA = __float2half2_rn(wA), whB = __float2half2_rn(wB);
    __half2 whC = __float2half2_rn(wC), whD = __float2half2_rn(wD);
    acc01 = __hfma2(whA, aA01, acc01); acc23 = __hfma2(whA, aA23, acc23);
    acc01 = __hfma2(whB, aB01, acc01); acc23 = __hfma2(whB, aB23, acc23);
    acc01 = __hfma2(whC, aC01, acc01); acc23 = __hfma2(whC, aC23, acc23);
    acc01 = __hfma2(whD, aD01, acc01); acc23 = __hfma2(whD, aD23, acc23);
    den += (wA + wB) + (wC + wD);
  }
  for (; j < deg; ++j){
    const unsigned sx = (unsigned)__builtin_amdgcn_readlane((int)m2.x, j);
    const unsigned sy = (unsigned)__builtin_amdgcn_readlane((int)m2.y, j);
    const unsigned he0 = (sx & 0xffffu) | (sx << 16);
    const unsigned he1 = (sx >> 16) | (sx & 0xffff0000u);
    const unsigned he2 = (sy & 0xffffu) | (sy << 16);
    uint2 u = *(const uint2*)(xlh + (size_t)(sy >> 16) * 256 + j0);
    const __half2 a01 = u2h2(u.x), a23 = u2h2(u.y);
    float p;
    EDGE_MATH(he0, he1, he2, a01, a23, p)
    p = sum16fast(p);
    float w = exp2fast(p);
    __half2 wh = __float2half2_rn(w);
    acc01 = __hfma2(wh, a01, acc01);
    acc23 = __hfma2(wh, a23, acc23);
    den += w;
  }

  // self loop (edge_attr = per-target mean of incoming edge attrs)
  {
    const float inv = 1.f / (float)max(deg, 1);
    const float e0 = waveSum64(s0) * inv;
    const float e1 = waveSum64(s1) * inv;
    const float e2 = waveSum64(s2) * inv;
    const __half2 he0h = __float2half2_rn(e0), he1h = __float2half2_rn(e1), he2h = __float2half2_rn(e2);
    uint2 u = *(const uint2*)(xlh + (size_t)n * 256 + j0);
    const __half2 a01 = u2h2(u.x), a23 = u2h2(u.y);
    __half2 z01 = __hadd2(a01, xr01);
    z01 = __hfma2(he0h, w0a, z01); z01 = __hfma2(he1h, w1a, z01); z01 = __hfma2(he2h, w2a, z01);
    __half2 z23 = __hadd2(a23, xr23);
    z23 = __hfma2(he0h, w0b, z23); z23 = __hfma2(he1h, w1b, z23); z23 = __hfma2(he2h, w2b, z23);
    z01 = hmax2(z01, __hmul2(z01, slp));
    z23 = hmax2(z23, __hmul2(z23, slp));
    float p = fdot2f(h22u(z01), awa, fdot2f(h22u(z23), awb, 0.f));
    p = sum16fast(p);
    float w = exp2fast(p);
    __half2 wh = __float2half2_rn(w);
    acc01 = __hfma2(wh, a01, acc01);
    acc23 = __hfma2(wh, a23, acc23);
    den += w;
  }

  // per-head normalize, sum over heads, head-mean + bias + residual + LN1
  float rd = 1.f / den;
  float4 o;
  o.x = __low2float(acc01) * rd; o.y = __high2float(acc01) * rd;
  o.z = __low2float(acc23) * rd; o.w = __high2float(acc23) * rd;
  o.x += __shfl_xor(o.x, 16); o.x += __shfl_xor(o.x, 32);
  o.y += __shfl_xor(o.y, 16); o.y += __shfl_xor(o.y, 32);
  o.z += __shfl_xor(o.z, 16); o.z += __shfl_xor(o.z, 32);
  o.w += __shfl_xor(o.w, 16); o.w += __shfl_xor(o.w, 32);
  const int c0 = (lane & 15) * 4;
  const float4 xv = *(const float4*)(x + (size_t)n * 64 + c0);
  const float4 gb = *(const float4*)(gat_b + c0);
  o.x = 0.25f * o.x + gb.x + xv.x;
  o.y = 0.25f * o.y + gb.y + xv.y;
  o.z = 0.25f * o.z + gb.z + xv.z;
  o.w = 0.25f * o.w + gb.w + xv.w;
  float t1 = sum16fast(o.x + o.y + o.z + o.w);
  float mu = t1 * (1.f / 64.f);
  float4 d; d.x = o.x - mu; d.y = o.y - mu; d.z = o.z - mu; d.w = o.w - mu;
  float t2 = sum16fast(d.x * d.x + d.y * d.y + d.z * d.z + d.w * d.w);
  float rs = rsqrtf(t2 * (1.f / 64.f) + LN_EPS);
  if (lane < 16){
    const float4 g4 = *(const float4*)(ln1g + c0);
    const float4 b4 = *(const float4*)(ln1b + c0);
    uint2 r;
    r.x = h22u(__floats2half2_rn(d.x * rs * g4.x + b4.x, d.y * rs * g4.y + b4.y));
    r.y = h22u(__floats2half2_rn(d.z * rs * g4.z + b4.z, d.w * rs * g4.w + b4.w));
    *(uint2*)(h1h + (size_t)n * 64 + c0) = r;
  }
}

// ---------------------------------------------------------------------------
// 4) FFN (64->128 lrelu ->64) packed f16 + residual + LN2 -> out
// ---------------------------------------------------------------------------
#define FT 32
__global__ void ffn_kernel(const __half* __restrict__ h1h,
                           const unsigned* __restrict__ W1p, const float* __restrict__ b1,
                           const unsigned* __restrict__ W2p, const float* __restrict__ b2,
                           const float* __restrict__ ln2g, const float* __restrict__ ln2b,
                           float* __restrict__ out){
  __shared__ __half2 hs2[FT][32];
  __shared__ __half  ts1[FT][128];
  __shared__ float   fs[FT][64];
  const int base = blockIdx.x * FT;
  const int tid = threadIdx.x;
  for (int i = tid; i < FT * 32; i += 256){
    int r = i >> 5, cc = i & 31;
    int n = base + r;
    unsigned hu = 0;
    if (n < N_NODES) hu = ((const unsigned*)(h1h + (size_t)n * 64))[cc];
    __half2 hv = u2h2(hu);
    hs2[r][cc] = hv;
    fs[r][cc * 2] = __low2float(hv); fs[r][cc * 2 + 1] = __high2float(hv);
  }
  __syncthreads();
  // layer 1: t = lrelu(h @ W1 + b1), f16
  {
    const int c1 = tid & 127, half = tid >> 7;
    __half2 acc[16];
#pragma unroll
    for (int i = 0; i < 16; ++i) acc[i] = __float2half2_rn(0.f);
    for (int kk = 0; kk < 32; kk += 2){
      __half2 wA = u2h2(W1p[(kk + 0) * 128 + c1]);
      __half2 wB = u2h2(W1p[(kk + 1) * 128 + c1]);
#pragma unroll
      for (int i = 0; i < 16; ++i){
        uint2 hv = *(const uint2*)&hs2[half * 16 + i][kk];
        acc[i] = __hfma2(u2h2(hv.x), wA, acc[i]);
        acc[i] = __hfma2(u2h2(hv.y), wB, acc[i]);
      }
    }
    const float b1c = b1[c1];
#pragma unroll
    for (int i = 0; i < 16; ++i){
      float t = __low2float(acc[i]) + __high2float(acc[i]) + b1c;
      ts1[half * 16 + i][c1] = __float2half(lrelu(t));
    }
  }
  __syncthreads();
  // layer 2: ffn = t @ W2 + b2 ; residual into fs  (W outer, rows inner)
  {
    const int c2 = tid & 63, qq = tid >> 6;
    __half2 acc2[8];
#pragma unroll
    for (int i = 0; i < 8; ++i) acc2[i] = __float2half2_rn(0.f);
    for (int kk = 0; kk < 64; kk += 2){
      __half2 wA = u2h2(W2p[(kk + 0) * 64 + c2]);
      __half2 wB = u2h2(W2p[(kk + 1) * 64 + c2]);
#pragma unroll
      for (int i = 0; i < 8; ++i){
        uint2 tt = *(const uint2*)&ts1[qq * 8 + i][2 * kk];
        acc2[i] = __hfma2(u2h2(tt.x), wA, acc2[i]);
        acc2[i] = __hfma2(u2h2(tt.y), wB, acc2[i]);
      }
    }
    const float b2c = b2[c2];
#pragma unroll
    for (int i = 0; i < 8; ++i)
      fs[qq * 8 + i][c2] += __low2float(acc2[i]) + __high2float(acc2[i]) + b2c;
  }
  __syncthreads();
  // LN2: wave q handles 8 rows; lane = channel
  {
    const int lane = tid & 63, qq = tid >> 6;
    const float g = ln2g[lane], bb = ln2b[lane];
    for (int i = 0; i < 8; ++i){
      int r = qq * 8 + i;
      int n = base + r;
      if (n >= N_NODES) break;
      float v = fs[r][lane];
      float mu = waveSum64(v) * (1.f / 64.f);
      float dlt = v - mu;
      float var = waveSum64(dlt * dlt) * (1.f / 64.f);
      out[(size_t)n * 64 + lane] = dlt * rsqrtf(var + LN_EPS) * g + bb;
    }
  }
}

// ---------------------------------------------------------------------------
extern "C" void kernel_launch(void* const* d_in, const int* in_sizes, int n_in,
                              void* d_out, int out_size, void* d_ws, size_t ws_size,
                              hipStream_t stream){
  const float* x     = (const float*)d_in[0];
  const int*   ei    = (const int*)  d_in[1];
  const float* ea    = (const float*)d_in[2];
  const float* Wl    = (const float*)d_in[3];
  const float* bl    = (const float*)d_in[4];
  const float* Wr    = (const float*)d_in[5];
  const float* br    = (const float*)d_in[6];
  const float* We    = (const float*)d_in[7];
  const float* att   = (const float*)d_in[8];
  const float* gat_b = (const float*)d_in[9];
  const float* ln1g  = (const float*)d_in[10];
  const float* ln1b  = (const float*)d_in[11];
  const float* ln2g  = (const float*)d_in[12];
  const float* ln2b  = (const float*)d_in[13];
  const float* W1    = (const float*)d_in[14];
  const float* b1    = (const float*)d_in[15];
  const float* W2    = (const float*)d_in[16];
  const float* b2    = (const float*)d_in[17];
  float* out = (float*)d_out;

  // workspace layout (~84 MB)
  uint2*    buckets = (uint2*)d_ws;                                   // N*64 (8B each)
  __half*   xlh     = (__half*)(buckets + (size_t)N_NODES * BCAP);    // N*256
  __half*   xrh     = xlh + (size_t)N_NODES * 256;                    // N*256
  __half*   h1h     = xrh + (size_t)N_NODES * 256;                    // N*64
  int*      cursor  = (int*)(h1h + (size_t)N_NODES * 64);             // N
  unsigned* W1p     = (unsigned*)(cursor + N_NODES);                  // 4096
  unsigned* W2p     = W1p + 4096;                                     // 4096

  (void)hipMemsetAsync(cursor, 0, (size_t)N_NODES * sizeof(int), stream);

  fill_kernel<<<(N_EDGES + 255) / 256, 256, 0, stream>>>(ei, ea, cursor, buckets, W1, W2, W1p, W2p);
  proj_kernel<<<PBLOCKS, 256, 0, stream>>>(x, Wl, bl, Wr, br, xlh, xrh);
  aggregate_kernel<<<N_NODES, 64, 0, stream>>>(
      cursor, buckets, xlh, xrh, We, att, x, gat_b, ln1g, ln1b, h1h);
  ffn_kernel<<<(N_NODES + FT - 1) / FT, 256, 0, stream>>>(h1h, W1p, b1, W2p, b2, ln2g, ln2b, out);
}

// Round 19
// 162.715 us; speedup vs baseline: 1.1011x; 1.1011x over previous
//
#include <hip/hip_runtime.h>
#include <hip/hip_fp16.h>

#ifndef __has_builtin
#define __has_builtin(x) 0
#endif

#define N_NODES 50000
#define N_EDGES 800000
#define DIM 64
#define NH 4
#define LN_EPS 1e-5f
#define SLOPE 0.2f
#define LOG2E 1.44269504f
#define PBLOCKS 782      // proj: 782 blocks x 64 nodes >= 50000
#define BCAP 64          // bucket capacity; P(Poisson(16) > 64) ~ 1e-18 per node

typedef _Float16 half4v __attribute__((ext_vector_type(4)));
typedef float floatx4 __attribute__((ext_vector_type(4)));

__device__ __forceinline__ float lrelu(float v){ return v > 0.f ? v : SLOPE * v; }

__device__ __forceinline__ float waveSum64(float v){
  v += __shfl_xor(v, 1);  v += __shfl_xor(v, 2);  v += __shfl_xor(v, 4);
  v += __shfl_xor(v, 8);  v += __shfl_xor(v, 16); v += __shfl_xor(v, 32);
  return v;
}

__device__ __forceinline__ __half2 u2h2(unsigned u){ union{unsigned u; __half2 h;} c; c.u = u; return c.h; }
__device__ __forceinline__ unsigned h22u(__half2 h){ union{unsigned u; __half2 h;} c; c.h = h; return c.u; }

// packed f16 max (no __hmax2 in ROCm headers) -> v_pk_max_f16
__device__ __forceinline__ __half2 hmax2(__half2 a, __half2 b){
  unsigned ua = h22u(a), ub = h22u(b), r;
  asm("v_pk_max_f16 %0, %1, %2" : "=v"(r) : "v"(ua), "v"(ub));
  return u2h2(r);
}

// f32 += dot(h2, h2) : v_dot2_f32_f16
__device__ __forceinline__ float fdot2f(unsigned a, unsigned b, float c){
#if __has_builtin(__builtin_amdgcn_fdot2)
  typedef _Float16 h2v __attribute__((ext_vector_type(2)));
  union U{unsigned u; h2v h;};
  U ua, ub; ua.u = a; ub.u = b;
  return __builtin_amdgcn_fdot2(ua.h, ub.h, c, false);
#else
  float r;
  asm("v_dot2_f32_f16 %0, %1, %2, %3" : "=v"(r) : "v"(a), "v"(b), "v"(c));
  return r;
#endif
}

__device__ __forceinline__ float exp2fast(float x){
#if __has_builtin(__builtin_amdgcn_exp2f)
  return __builtin_amdgcn_exp2f(x);
#else
  float r; asm("v_exp_f32 %0, %1" : "=v"(r) : "v"(x)); return r;
#endif
}

// single 16-lane row reduce (tail / epilogue use)
__device__ __forceinline__ float sum16fast(float v){
  asm("s_nop 1\n\t"
      "v_add_f32_dpp %0, %0, %0 quad_perm:[1,0,3,2] row_mask:0xf bank_mask:0xf\n\t"
      "s_nop 1\n\t"
      "v_add_f32_dpp %0, %0, %0 quad_perm:[2,3,0,1] row_mask:0xf bank_mask:0xf\n\t"
      "s_nop 1\n\t"
      "v_add_f32_dpp %0, %0, %0 row_ror:4 row_mask:0xf bank_mask:0xf\n\t"
      "s_nop 1\n\t"
      "v_add_f32_dpp %0, %0, %0 row_ror:8 row_mask:0xf bank_mask:0xf"
      : "+v"(v));
  return v;
}

// quad 16-lane reduce: 4 independent chains interleaved -> zero hazard nops
__device__ __forceinline__ void sum16quad(float& a, float& b, float& c, float& d){
  asm("v_add_f32_dpp %0, %0, %0 quad_perm:[1,0,3,2] row_mask:0xf bank_mask:0xf\n\t"
      "v_add_f32_dpp %1, %1, %1 quad_perm:[1,0,3,2] row_mask:0xf bank_mask:0xf\n\t"
      "v_add_f32_dpp %2, %2, %2 quad_perm:[1,0,3,2] row_mask:0xf bank_mask:0xf\n\t"
      "v_add_f32_dpp %3, %3, %3 quad_perm:[1,0,3,2] row_mask:0xf bank_mask:0xf\n\t"
      "v_add_f32_dpp %0, %0, %0 quad_perm:[2,3,0,1] row_mask:0xf bank_mask:0xf\n\t"
      "v_add_f32_dpp %1, %1, %1 quad_perm:[2,3,0,1] row_mask:0xf bank_mask:0xf\n\t"
      "v_add_f32_dpp %2, %2, %2 quad_perm:[2,3,0,1] row_mask:0xf bank_mask:0xf\n\t"
      "v_add_f32_dpp %3, %3, %3 quad_perm:[2,3,0,1] row_mask:0xf bank_mask:0xf\n\t"
      "v_add_f32_dpp %0, %0, %0 row_ror:4 row_mask:0xf bank_mask:0xf\n\t"
      "v_add_f32_dpp %1, %1, %1 row_ror:4 row_mask:0xf bank_mask:0xf\n\t"
      "v_add_f32_dpp %2, %2, %2 row_ror:4 row_mask:0xf bank_mask:0xf\n\t"
      "v_add_f32_dpp %3, %3, %3 row_ror:4 row_mask:0xf bank_mask:0xf\n\t"
      "v_add_f32_dpp %0, %0, %0 row_ror:8 row_mask:0xf bank_mask:0xf\n\t"
      "v_add_f32_dpp %1, %1, %1 row_ror:8 row_mask:0xf bank_mask:0xf\n\t"
      "v_add_f32_dpp %2, %2, %2 row_ror:8 row_mask:0xf bank_mask:0xf\n\t"
      "v_add_f32_dpp %3, %3, %3 row_ror:8 row_mask:0xf bank_mask:0xf"
      : "+v"(a), "+v"(b), "+v"(c), "+v"(d));
}

// ---------------------------------------------------------------------------
// 1) proj v7: MFMA GEMM + fused pipelined edge fill (r17 structure, which
// measured 72us combined vs 88us split in r18) + padded ot[16][520] (r18's
// fix: 16B-aligned rows, <=2-way LDS aliasing; r17 had 800K conflicts).
// Wave w owns cols [128w,128w+128) of concat(Wl,Wr), B-frags in regs.
// ---------------------------------------------------------------------------
__global__ __launch_bounds__(256)
void proj_kernel(const float* __restrict__ x,
                 const float* __restrict__ Wl, const float* __restrict__ bl,
                 const float* __restrict__ Wr, const float* __restrict__ br,
                 __half* __restrict__ xlh, __half* __restrict__ xrh,
                 const int* __restrict__ ei, const float* __restrict__ ea,
                 int* __restrict__ cursor, uint2* __restrict__ buckets,
                 const float* __restrict__ W1, const float* __restrict__ W2,
                 unsigned* __restrict__ W1p, unsigned* __restrict__ W2p){
  __shared__ __half ot[16][520];     // 16.25 KB output staging (padded)
  const int tid = threadIdx.x;
  const int lane = tid & 63, w = tid >> 6;
  const int row = lane & 15, kg = lane >> 4;

  // fused FFN weight packing (first 32 blocks)
  const int gid0 = blockIdx.x * 256 + tid;
  if (gid0 < 4096){
    int kk = gid0 >> 7, cc = gid0 & 127;
    W1p[gid0] = h22u(__floats2half2_rn(W1[(2 * kk) * 128 + cc], W1[(2 * kk + 1) * 128 + cc]));
  } else if (gid0 < 8192){
    int j = gid0 - 4096;
    int kk = j >> 6, cc = j & 63;
    W2p[j] = h22u(__floats2half2_rn(W2[(2 * kk) * 64 + cc], W2[(2 * kk + 1) * 64 + cc]));
  }

  // ---- phase A: 4 edges per thread (loads + atomics issue early) ----
  int edst[4], epos[4]; uint2 epk[4]; bool ehas[4];
#pragma unroll
  for (int q = 0; q < 4; ++q){
    const int e = gid0 + q * (PBLOCKS * 256);
    ehas[q] = e < N_EDGES;
    const int ec = ehas[q] ? e : 0;
    edst[q] = ei[N_EDGES + ec];
    const int src = ei[ec];
    const float e0 = ea[ec * 3 + 0], e1 = ea[ec * 3 + 1], e2 = ea[ec * 3 + 2];
    epk[q].x = h22u(__floats2half2_rn(e0, e1));
    epk[q].y = (h22u(__floats2half2_rn(e2, 0.f)) & 0xffffu) | ((unsigned)src << 16);
    epos[q] = ehas[q] ? atomicAdd(&cursor[edst[q]], 1) : 0;
  }

  // ---- B fragments (once per wave; reused over 4 M-tiles) ----
  const int colb = w * 128;               // global col base of this wave
  const bool isL = colb < 256;
  const float* Wb = isL ? Wl : Wr;
  const float* bb = isL ? bl : br;
  const int cl = colb & 255;              // 0 or 128 within the matrix
  half4v bf[8][4];
  float bias[8];
#pragma unroll
  for (int nt = 0; nt < 8; ++nt){
    const int c = cl + nt * 16 + row;
    bias[nt] = bb[c];
#pragma unroll
    for (int kc = 0; kc < 4; ++kc){
      half4v b;
#pragma unroll
      for (int e = 0; e < 4; ++e)
        b[e] = (_Float16)Wb[(kc * 16 + kg * 4 + e) * 256 + c];
      bf[nt][kc] = b;
    }
  }

  // ---- M loop: 4 tiles of 16 nodes ----
  const int nbase = blockIdx.x * 64;
  for (int m = 0; m < 4; ++m){
    const int nb = nbase + m * 16;
    if (nb >= N_NODES) break;
    const int nld = min(nb + row, N_NODES - 1);
    half4v af[4];
#pragma unroll
    for (int kc = 0; kc < 4; ++kc){
      const float4 xv = *(const float4*)&x[(size_t)nld * 64 + kc * 16 + kg * 4];
      half4v a;
      a[0] = (_Float16)xv.x; a[1] = (_Float16)xv.y;
      a[2] = (_Float16)xv.z; a[3] = (_Float16)xv.w;
      af[kc] = a;
    }
    __syncthreads();   // ot free from previous tile's stores
#pragma unroll
    for (int nt = 0; nt < 8; ++nt){
      floatx4 acc = {0.f, 0.f, 0.f, 0.f};
      acc = __builtin_amdgcn_mfma_f32_16x16x16f16(af[0], bf[nt][0], acc, 0, 0, 0);
      acc = __builtin_amdgcn_mfma_f32_16x16x16f16(af[1], bf[nt][1], acc, 0, 0, 0);
      acc = __builtin_amdgcn_mfma_f32_16x16x16f16(af[2], bf[nt][2], acc, 0, 0, 0);
      acc = __builtin_amdgcn_mfma_f32_16x16x16f16(af[3], bf[nt][3], acc, 0, 0, 0);
      const int c = w * 128 + nt * 16 + row;      // 0..511 within concat
#pragma unroll
      for (int r = 0; r < 4; ++r)
        ot[kg * 4 + r][c] = __float2half(acc[r] + bias[nt]);
    }
    __syncthreads();
    // coalesced store: 1024 uint4 per tile, 4 per thread
#pragma unroll
    for (int s = 0; s < 4; ++s){
      const int idx = s * 256 + tid;
      const int r = idx >> 6, q = idx & 63;
      const int n = nb + r;
      if (n < N_NODES){
        const uint4 v = *(const uint4*)&ot[r][q * 8];
        if (q < 32) *(uint4*)(xlh + (size_t)n * 256 + q * 8) = v;
        else        *(uint4*)(xrh + (size_t)n * 256 + (q - 32) * 8) = v;
      }
    }
  }

  // ---- phase C: commit edge bucket stores ----
#pragma unroll
  for (int q = 0; q < 4; ++q){
    if (ehas[q]){
      const int p = min(epos[q], BCAP - 1);
      buckets[(size_t)edst[q] * BCAP + p] = epk[q];
    }
  }
}

// ---------------------------------------------------------------------------
// 2) FUSED GATv2: logits + segment softmax + aggregation + self-loop
//    + head mean + gat_b + residual + LN1.  ONE WAVE = ONE BLOCK = ONE NODE
// ---------------------------------------------------------------------------
#define EDGE_MATH(he0, he1, he2, a01, a23, p)                                        \
  {                                                                                  \
    __half2 z01 = __hadd2(a01, xr01);                                                \
    z01 = __hfma2(u2h2(he0), w0a, z01);                                              \
    z01 = __hfma2(u2h2(he1), w1a, z01);                                              \
    z01 = __hfma2(u2h2(he2), w2a, z01);                                              \
    __half2 z23 = __hadd2(a23, xr23);                                                \
    z23 = __hfma2(u2h2(he0), w0b, z23);                                              \
    z23 = __hfma2(u2h2(he1), w1b, z23);                                              \
    z23 = __hfma2(u2h2(he2), w2b, z23);                                              \
    z01 = hmax2(z01, __hmul2(z01, slp));                                             \
    z23 = hmax2(z23, __hmul2(z23, slp));                                             \
    p = fdot2f(h22u(z01), awa, fdot2f(h22u(z23), awb, 0.f));                         \
  }

__global__ __launch_bounds__(64)
void aggregate_kernel(const int* __restrict__ cursor, const uint2* __restrict__ buckets,
                      const __half* __restrict__ xlh, const __half* __restrict__ xrh,
                      const float* __restrict__ We, const float* __restrict__ att,
                      const float* __restrict__ x, const float* __restrict__ gat_b,
                      const float* __restrict__ ln1g, const float* __restrict__ ln1b,
                      __half* __restrict__ h1h){
  const int n = blockIdx.x;
  const int lane = threadIdx.x;
  const int j0 = lane * 4;
  const unsigned awa = h22u(__floats2half2_rn(att[j0] * LOG2E, att[j0 + 1] * LOG2E));
  const unsigned awb = h22u(__floats2half2_rn(att[j0 + 2] * LOG2E, att[j0 + 3] * LOG2E));
  const __half2 w0a = __floats2half2_rn(We[j0], We[j0 + 1]);
  const __half2 w0b = __floats2half2_rn(We[j0 + 2], We[j0 + 3]);
  const __half2 w1a = __floats2half2_rn(We[256 + j0], We[256 + j0 + 1]);
  const __half2 w1b = __floats2half2_rn(We[256 + j0 + 2], We[256 + j0 + 3]);
  const __half2 w2a = __floats2half2_rn(We[512 + j0], We[512 + j0 + 1]);
  const __half2 w2b = __floats2half2_rn(We[512 + j0 + 2], We[512 + j0 + 3]);
  const __half2 slp = __float2half2_rn(SLOPE);
  uint2 uxr = *(const uint2*)(xrh + (size_t)n * 256 + j0);
  const __half2 xr01 = u2h2(uxr.x), xr23 = u2h2(uxr.y);

  __half2 acc01 = __float2half2_rn(0.f), acc23 = __float2half2_rn(0.f);
  float den = 0.f;
  const int deg = min(cursor[n], BCAP);
  uint2 m2; m2.x = 0; m2.y = 0;
  if (lane < deg) m2 = buckets[(size_t)n * BCAP + lane];
  float s0 = __low2float(u2h2(m2.x));
  float s1 = __high2float(u2h2(m2.x));
  float s2 = __low2float(u2h2(m2.y & 0xffffu));
  int j = 0;
  for (; j + 4 <= deg; j += 4){
    const unsigned sxA = (unsigned)__builtin_amdgcn_readlane((int)m2.x, j);
    const unsigned syA = (unsigned)__builtin_amdgcn_readlane((int)m2.y, j);
    const unsigned sxB = (unsigned)__builtin_amdgcn_readlane((int)m2.x, j + 1);
    const unsigned syB = (unsigned)__builtin_amdgcn_readlane((int)m2.y, j + 1);
    const unsigned sxC = (unsigned)__builtin_amdgcn_readlane((int)m2.x, j + 2);
    const unsigned syC = (unsigned)__builtin_amdgcn_readlane((int)m2.y, j + 2);
    const unsigned sxD = (unsigned)__builtin_amdgcn_readlane((int)m2.x, j + 3);
    const unsigned syD = (unsigned)__builtin_amdgcn_readlane((int)m2.y, j + 3);
    uint2 uA = *(const uint2*)(xlh + (size_t)(syA >> 16) * 256 + j0);
    uint2 uB = *(const uint2*)(xlh + (size_t)(syB >> 16) * 256 + j0);
    uint2 uC = *(const uint2*)(xlh + (size_t)(syC >> 16) * 256 + j0);
    uint2 uD = *(const uint2*)(xlh + (size_t)(syD >> 16) * 256 + j0);
    const unsigned heA0 = (sxA & 0xffffu) | (sxA << 16), heA1 = (sxA >> 16) | (sxA & 0xffff0000u), heA2 = (syA & 0xffffu) | (syA << 16);
    const unsigned heB0 = (sxB & 0xffffu) | (sxB << 16), heB1 = (sxB >> 16) | (sxB & 0xffff0000u), heB2 = (syB & 0xffffu) | (syB << 16);
    const unsigned heC0 = (sxC & 0xffffu) | (sxC << 16), heC1 = (sxC >> 16) | (sxC & 0xffff0000u), heC2 = (syC & 0xffffu) | (syC << 16);
    const unsigned heD0 = (sxD & 0xffffu) | (sxD << 16), heD1 = (sxD >> 16) | (sxD & 0xffff0000u), heD2 = (syD & 0xffffu) | (syD << 16);
    const __half2 aA01 = u2h2(uA.x), aA23 = u2h2(uA.y);
    const __half2 aB01 = u2h2(uB.x), aB23 = u2h2(uB.y);
    const __half2 aC01 = u2h2(uC.x), aC23 = u2h2(uC.y);
    const __half2 aD01 = u2h2(uD.x), aD23 = u2h2(uD.y);
    float pA, pB, pC, pD;
    EDGE_MATH(heA0, heA1, heA2, aA01, aA23, pA)
    EDGE_MATH(heB0, heB1, heB2, aB01, aB23, pB)
    EDGE_MATH(heC0, heC1, heC2, aC01, aC23, pC)
    EDGE_MATH(heD0, heD1, heD2, aD01, aD23, pD)
    sum16quad(pA, pB, pC, pD);
    float wA = exp2fast(pA), wB = exp2fast(pB);
    float wC = exp2fast(pC), wD = exp2fast(pD);
    __half2 whA = __float2half2_rn(wA), whB = __float2half2_rn(wB);
    __half2 whC = __float2half2_rn(wC), whD = __float2half2_rn(wD);
    acc01 = __hfma2(whA, aA01, acc01); acc23 = __hfma2(whA, aA23, acc23);
    acc01 = __hfma2(whB, aB01, acc01); acc23 = __hfma2(whB, aB23, acc23);
    acc01 = __hfma2(whC, aC01, acc01); acc23 = __hfma2(whC, aC23, acc23);
    acc01 = __hfma2(whD, aD01, acc01); acc23 = __hfma2(whD, aD23, acc23);
    den += (wA + wB) + (wC + wD);
  }
  for (; j < deg; ++j){
    const unsigned sx = (unsigned)__builtin_amdgcn_readlane((int)m2.x, j);
    const unsigned sy = (unsigned)__builtin_amdgcn_readlane((int)m2.y, j);
    const unsigned he0 = (sx & 0xffffu) | (sx << 16);
    const unsigned he1 = (sx >> 16) | (sx & 0xffff0000u);
    const unsigned he2 = (sy & 0xffffu) | (sy << 16);
    uint2 u = *(const uint2*)(xlh + (size_t)(sy >> 16) * 256 + j0);
    const __half2 a01 = u2h2(u.x), a23 = u2h2(u.y);
    float p;
    EDGE_MATH(he0, he1, he2, a01, a23, p)
    p = sum16fast(p);
    float w = exp2fast(p);
    __half2 wh = __float2half2_rn(w);
    acc01 = __hfma2(wh, a01, acc01);
    acc23 = __hfma2(wh, a23, acc23);
    den += w;
  }

  // self loop (edge_attr = per-target mean of incoming edge attrs)
  {
    const float inv = 1.f / (float)max(deg, 1);
    const float e0 = waveSum64(s0) * inv;
    const float e1 = waveSum64(s1) * inv;
    const float e2 = waveSum64(s2) * inv;
    const __half2 he0h = __float2half2_rn(e0), he1h = __float2half2_rn(e1), he2h = __float2half2_rn(e2);
    uint2 u = *(const uint2*)(xlh + (size_t)n * 256 + j0);
    const __half2 a01 = u2h2(u.x), a23 = u2h2(u.y);
    __half2 z01 = __hadd2(a01, xr01);
    z01 = __hfma2(he0h, w0a, z01); z01 = __hfma2(he1h, w1a, z01); z01 = __hfma2(he2h, w2a, z01);
    __half2 z23 = __hadd2(a23, xr23);
    z23 = __hfma2(he0h, w0b, z23); z23 = __hfma2(he1h, w1b, z23); z23 = __hfma2(he2h, w2b, z23);
    z01 = hmax2(z01, __hmul2(z01, slp));
    z23 = hmax2(z23, __hmul2(z23, slp));
    float p = fdot2f(h22u(z01), awa, fdot2f(h22u(z23), awb, 0.f));
    p = sum16fast(p);
    float w = exp2fast(p);
    __half2 wh = __float2half2_rn(w);
    acc01 = __hfma2(wh, a01, acc01);
    acc23 = __hfma2(wh, a23, acc23);
    den += w;
  }

  // per-head normalize, sum over heads, head-mean + bias + residual + LN1
  float rd = 1.f / den;
  float4 o;
  o.x = __low2float(acc01) * rd; o.y = __high2float(acc01) * rd;
  o.z = __low2float(acc23) * rd; o.w = __high2float(acc23) * rd;
  o.x += __shfl_xor(o.x, 16); o.x += __shfl_xor(o.x, 32);
  o.y += __shfl_xor(o.y, 16); o.y += __shfl_xor(o.y, 32);
  o.z += __shfl_xor(o.z, 16); o.z += __shfl_xor(o.z, 32);
  o.w += __shfl_xor(o.w, 16); o.w += __shfl_xor(o.w, 32);
  const int c0 = (lane & 15) * 4;
  const float4 xv = *(const float4*)(x + (size_t)n * 64 + c0);
  const float4 gb = *(const float4*)(gat_b + c0);
  o.x = 0.25f * o.x + gb.x + xv.x;
  o.y = 0.25f * o.y + gb.y + xv.y;
  o.z = 0.25f * o.z + gb.z + xv.z;
  o.w = 0.25f * o.w + gb.w + xv.w;
  float t1 = sum16fast(o.x + o.y + o.z + o.w);
  float mu = t1 * (1.f / 64.f);
  float4 d; d.x = o.x - mu; d.y = o.y - mu; d.z = o.z - mu; d.w = o.w - mu;
  float t2 = sum16fast(d.x * d.x + d.y * d.y + d.z * d.z + d.w * d.w);
  float rs = rsqrtf(t2 * (1.f / 64.f) + LN_EPS);
  if (lane < 16){
    const float4 g4 = *(const float4*)(ln1g + c0);
    const float4 b4 = *(const float4*)(ln1b + c0);
    uint2 r;
    r.x = h22u(__floats2half2_rn(d.x * rs * g4.x + b4.x, d.y * rs * g4.y + b4.y));
    r.y = h22u(__floats2half2_rn(d.z * rs * g4.z + b4.z, d.w * rs * g4.w + b4.w));
    *(uint2*)(h1h + (size_t)n * 64 + c0) = r;
  }
}

// ---------------------------------------------------------------------------
// 3) FFN (64->128 lrelu ->64) packed f16 + residual + LN2 -> out
// ---------------------------------------------------------------------------
#define FT 32
__global__ void ffn_kernel(const __half* __restrict__ h1h,
                           const unsigned* __restrict__ W1p, const float* __restrict__ b1,
                           const unsigned* __restrict__ W2p, const float* __restrict__ b2,
                           const float* __restrict__ ln2g, const float* __restrict__ ln2b,
                           float* __restrict__ out){
  __shared__ __half2 hs2[FT][32];
  __shared__ __half  ts1[FT][128];
  __shared__ float   fs[FT][64];
  const int base = blockIdx.x * FT;
  const int tid = threadIdx.x;
  for (int i = tid; i < FT * 32; i += 256){
    int r = i >> 5, cc = i & 31;
    int n = base + r;
    unsigned hu = 0;
    if (n < N_NODES) hu = ((const unsigned*)(h1h + (size_t)n * 64))[cc];
    __half2 hv = u2h2(hu);
    hs2[r][cc] = hv;
    fs[r][cc * 2] = __low2float(hv); fs[r][cc * 2 + 1] = __high2float(hv);
  }
  __syncthreads();
  // layer 1: t = lrelu(h @ W1 + b1), f16
  {
    const int c1 = tid & 127, half = tid >> 7;
    __half2 acc[16];
#pragma unroll
    for (int i = 0; i < 16; ++i) acc[i] = __float2half2_rn(0.f);
    for (int kk = 0; kk < 32; kk += 2){
      __half2 wA = u2h2(W1p[(kk + 0) * 128 + c1]);
      __half2 wB = u2h2(W1p[(kk + 1) * 128 + c1]);
#pragma unroll
      for (int i = 0; i < 16; ++i){
        uint2 hv = *(const uint2*)&hs2[half * 16 + i][kk];
        acc[i] = __hfma2(u2h2(hv.x), wA, acc[i]);
        acc[i] = __hfma2(u2h2(hv.y), wB, acc[i]);
      }
    }
    const float b1c = b1[c1];
#pragma unroll
    for (int i = 0; i < 16; ++i){
      float t = __low2float(acc[i]) + __high2float(acc[i]) + b1c;
      ts1[half * 16 + i][c1] = __float2half(lrelu(t));
    }
  }
  __syncthreads();
  // layer 2: ffn = t @ W2 + b2 ; residual into fs  (W outer, rows inner)
  {
    const int c2 = tid & 63, qq = tid >> 6;
    __half2 acc2[8];
#pragma unroll
    for (int i = 0; i < 8; ++i) acc2[i] = __float2half2_rn(0.f);
    for (int kk = 0; kk < 64; kk += 2){
      __half2 wA = u2h2(W2p[(kk + 0) * 64 + c2]);
      __half2 wB = u2h2(W2p[(kk + 1) * 64 + c2]);
#pragma unroll
      for (int i = 0; i < 8; ++i){
        uint2 tt = *(const uint2*)&ts1[qq * 8 + i][2 * kk];
        acc2[i] = __hfma2(u2h2(tt.x), wA, acc2[i]);
        acc2[i] = __hfma2(u2h2(tt.y), wB, acc2[i]);
      }
    }
    const float b2c = b2[c2];
#pragma unroll
    for (int i = 0; i < 8; ++i)
      fs[qq * 8 + i][c2] += __low2float(acc2[i]) + __high2float(acc2[i]) + b2c;
  }
  __syncthreads();
  // LN2: wave q handles 8 rows; lane = channel
  {
    const int lane = tid & 63, qq = tid >> 6;
    const float g = ln2g[lane], bb = ln2b[lane];
    for (int i = 0; i < 8; ++i){
      int r = qq * 8 + i;
      int n = base + r;
      if (n >= N_NODES) break;
      float v = fs[r][lane];
      float mu = waveSum64(v) * (1.f / 64.f);
      float dlt = v - mu;
      float var = waveSum64(dlt * dlt) * (1.f / 64.f);
      out[(size_t)n * 64 + lane] = dlt * rsqrtf(var + LN_EPS) * g + bb;
    }
  }
}

// ---------------------------------------------------------------------------
extern "C" void kernel_launch(void* const* d_in, const int* in_sizes, int n_in,
                              void* d_out, int out_size, void* d_ws, size_t ws_size,
                              hipStream_t stream){
  const float* x     = (const float*)d_in[0];
  const int*   ei    = (const int*)  d_in[1];
  const float* ea    = (const float*)d_in[2];
  const float* Wl    = (const float*)d_in[3];
  const float* bl    = (const float*)d_in[4];
  const float* Wr    = (const float*)d_in[5];
  const float* br    = (const float*)d_in[6];
  const float* We    = (const float*)d_in[7];
  const float* att   = (const float*)d_in[8];
  const float* gat_b = (const float*)d_in[9];
  const float* ln1g  = (const float*)d_in[10];
  const float* ln1b  = (const float*)d_in[11];
  const float* ln2g  = (const float*)d_in[12];
  const float* ln2b  = (const float*)d_in[13];
  const float* W1    = (const float*)d_in[14];
  const float* b1    = (const float*)d_in[15];
  const float* W2    = (const float*)d_in[16];
  const float* b2    = (const float*)d_in[17];
  float* out = (float*)d_out;

  // workspace layout (~84 MB)
  uint2*    buckets = (uint2*)d_ws;                                   // N*64 (8B each)
  __half*   xlh     = (__half*)(buckets + (size_t)N_NODES * BCAP);    // N*256
  __half*   xrh     = xlh + (size_t)N_NODES * 256;                    // N*256
  __half*   h1h     = xrh + (size_t)N_NODES * 256;                    // N*64
  int*      cursor  = (int*)(h1h + (size_t)N_NODES * 64);             // N
  unsigned* W1p     = (unsigned*)(cursor + N_NODES);                  // 4096
  unsigned* W2p     = W1p + 4096;                                     // 4096

  (void)hipMemsetAsync(cursor, 0, (size_t)N_NODES * sizeof(int), stream);

  proj_kernel<<<PBLOCKS, 256, 0, stream>>>(x, Wl, bl, Wr, br, xlh, xrh,
                                           ei, ea, cursor, buckets, W1, W2, W1p, W2p);
  aggregate_kernel<<<N_NODES, 64, 0, stream>>>(
      cursor, buckets, xlh, xrh, We, att, x, gat_b, ln1g, ln1b, h1h);
  ffn_kernel<<<(N_NODES + FT - 1) / FT, 256, 0, stream>>>(h1h, W1p, b1, W2p, b2, ln2g, ln2b, out);
}